// Round 1
// baseline (199.745 us; speedup 1.0000x reference)
//
#include <hip/hip_runtime.h>

typedef short short8 __attribute__((ext_vector_type(8)));
typedef unsigned short ushort8 __attribute__((ext_vector_type(8)));
typedef float f32x4 __attribute__((ext_vector_type(4)));

__device__ __forceinline__ unsigned short f32_to_bf16(float f) {
  unsigned u = __float_as_uint(f);
  unsigned r = 0x7fffu + ((u >> 16) & 1u);
  return (unsigned short)((u + r) >> 16);
}
__device__ __forceinline__ float bf16_to_f32(unsigned short h) {
  return __uint_as_float(((unsigned)h) << 16);
}

// ---------------- f32 -> bf16 convert (vectorized, 8 elems/thread) ----------
__global__ void cvt_f32_bf16(const float* __restrict__ s,
                             unsigned short* __restrict__ d, int n8) {
  int i = blockIdx.x * blockDim.x + threadIdx.x;
  if (i >= n8) return;
  const float4* sp = (const float4*)s;
  float4 a = sp[2 * i], b = sp[2 * i + 1];
  ushort8 o;
  o[0] = f32_to_bf16(a.x); o[1] = f32_to_bf16(a.y);
  o[2] = f32_to_bf16(a.z); o[3] = f32_to_bf16(a.w);
  o[4] = f32_to_bf16(b.x); o[5] = f32_to_bf16(b.y);
  o[6] = f32_to_bf16(b.z); o[7] = f32_to_bf16(b.w);
  ((ushort8*)d)[i] = o;
}

// ---------------- async global->LDS (16B/lane, wave-uniform LDS base) -------
__device__ __forceinline__ void gload_lds16(const void* g, void* l) {
  auto* gp = (const __attribute__((address_space(1))) uint32_t*)((uintptr_t)g);
  // generic LDS pointer: low 32 bits are the LDS offset (CK pattern)
  auto* lp = (__attribute__((address_space(3))) uint32_t*)(uint32_t)(uintptr_t)l;
  __builtin_amdgcn_global_load_lds(gp, lp, 16, 0, 0);
}

// ---------------- bf16 MFMA GEMM, C = A * B^T + bias ------------------------
// A [M,K] bf16 row-major, B [N,K] bf16 row-major. 128x128 tile, BK=64,
// 4 waves, each wave owns a 64x64 sub-tile (4x4 of 16x16 frags). m97 structure.
template <int OUT_BF16>
__global__ __launch_bounds__(256) void gemm_bt(
    const unsigned short* __restrict__ A, const unsigned short* __restrict__ B,
    const float* __restrict__ bias, void* __restrict__ out,
    int M, int N, int K) {
  __shared__ __align__(16) unsigned short As[128 * 64];
  __shared__ __align__(16) unsigned short Bs[128 * 64];

  const int tid = threadIdx.x;
  const int lane = tid & 63;
  const int wid = tid >> 6;
  const int wr = wid >> 1, wc = wid & 1;
  const int m0 = blockIdx.y * 128, n0 = blockIdx.x * 128;

  const int lr8 = lane >> 3;        // row within an 8-row staging chunk
  const int lc8 = (lane & 7) * 8;   // k-offset (8 bf16 = 16B per lane)

  f32x4 acc[4][4] = {};

  for (int k0 = 0; k0 < K; k0 += 64) {
    __syncthreads();  // prior compute done before LDS overwrite
#pragma unroll
    for (int c = 0; c < 4; ++c) {
      const int rowc = wid * 32 + c * 8;  // wave-uniform LDS chunk base
      gload_lds16(A + (size_t)(m0 + rowc + lr8) * K + (k0 + lc8), &As[rowc * 64]);
      gload_lds16(B + (size_t)(n0 + rowc + lr8) * K + (k0 + lc8), &Bs[rowc * 64]);
    }
    __syncthreads();  // drains vmcnt -> staged tile visible

    const int rsel = lane & 15;
#pragma unroll
    for (int ks = 0; ks < 2; ++ks) {
      const int kofs = ks * 32 + (lane >> 4) * 8;
      short8 af[4], bf[4];
#pragma unroll
      for (int m = 0; m < 4; ++m)
        af[m] = *(const short8*)&As[(wr * 64 + m * 16 + rsel) * 64 + kofs];
#pragma unroll
      for (int n = 0; n < 4; ++n)
        bf[n] = *(const short8*)&Bs[(wc * 64 + n * 16 + rsel) * 64 + kofs];
#pragma unroll
      for (int m = 0; m < 4; ++m)
#pragma unroll
        for (int n = 0; n < 4; ++n)
          acc[m][n] = __builtin_amdgcn_mfma_f32_16x16x32_bf16(
              af[m], bf[n], acc[m][n], 0, 0, 0);
    }
  }

  // C/D layout (m89-verified): col = lane&15, row = (lane>>4)*4 + j
  const int fr = lane & 15, fq = lane >> 4;
#pragma unroll
  for (int n = 0; n < 4; ++n) {
    const int gcol = n0 + wc * 64 + n * 16 + fr;
    const float bv = bias[gcol];
#pragma unroll
    for (int m = 0; m < 4; ++m) {
      const int grow = m0 + wr * 64 + m * 16 + fq * 4;
#pragma unroll
      for (int j = 0; j < 4; ++j) {
        float v = acc[m][n][j] + bv;
        if (OUT_BF16)
          ((unsigned short*)out)[(size_t)(grow + j) * N + gcol] = f32_to_bf16(v);
        else
          ((float*)out)[(size_t)(grow + j) * N + gcol] = v;
      }
    }
  }
}

// ---------------- 16-point DFT (radix 4x4, constant twiddles) ---------------
constexpr float C16T[16] = {
    1.f,  0.9238795325112867f,  0.7071067811865476f,  0.3826834323650898f,
    0.f, -0.3826834323650898f, -0.7071067811865476f, -0.9238795325112867f,
   -1.f, -0.9238795325112867f, -0.7071067811865476f, -0.3826834323650898f,
    0.f,  0.3826834323650898f,  0.7071067811865476f,  0.9238795325112867f};
constexpr float S16T[16] = {
    0.f,  0.3826834323650898f,  0.7071067811865476f,  0.9238795325112867f,
    1.f,  0.9238795325112867f,  0.7071067811865476f,  0.3826834323650898f,
    0.f, -0.3826834323650898f, -0.7071067811865476f, -0.9238795325112867f,
   -1.f, -0.9238795325112867f, -0.7071067811865476f, -0.3826834323650898f};

// X[u] = sum_c x[c] * e^{sgn*2*pi*i*u*c/16};  sgn=-1 forward, +1 inverse (unnormalized)
__device__ __forceinline__ void dft16(const float* xr, const float* xi,
                                      float* Xr, float* Xi, const float sgn) {
  float Tr[4][4], Ti[4][4];
#pragma unroll
  for (int c0 = 0; c0 < 4; ++c0) {
    float ar = xr[c0],      ai = xi[c0];
    float br = xr[c0 + 4],  bi = xi[c0 + 4];
    float cr = xr[c0 + 8],  ci = xi[c0 + 8];
    float dr = xr[c0 + 12], di = xi[c0 + 12];
    float Er = ar + cr, Ei = ai + ci, Fr = ar - cr, Fi = ai - ci;
    float Gr = br + dr, Gi = bi + di, Hr = br - dr, Hi = bi - di;
    Tr[c0][0] = Er + Gr; Ti[c0][0] = Ei + Gi;
    Tr[c0][2] = Er - Gr; Ti[c0][2] = Ei - Gi;
    float wHr = -sgn * Hi, wHi = sgn * Hr;  // (i*sgn)*H
    Tr[c0][1] = Fr + wHr; Ti[c0][1] = Fi + wHi;
    Tr[c0][3] = Fr - wHr; Ti[c0][3] = Fi - wHi;
  }
#pragma unroll
  for (int u = 0; u < 16; ++u) {
    const int m = u & 3;
    float sr = Tr[0][m], si = Ti[0][m];
#pragma unroll
    for (int c0 = 1; c0 < 4; ++c0) {
      const int k = (u * c0) & 15;
      const float wr = C16T[k];
      const float wi = sgn * S16T[k];
      sr += wr * Tr[c0][m] - wi * Ti[c0][m];
      si += wr * Ti[c0][m] + wi * Tr[c0][m];
    }
    Xr[u] = sr; Xi[u] = si;
  }
}

// ---------------- per-patch fft2 -> filter -> ifft2 -> abs (in place) -------
// h: [nPatchCh, 256] bf16 (viewed as 16x16). 16 patch-channels per 256-thread
// block; thread = (p = tid>>4, q = tid&15). LDS padded: row stride 17 float2,
// patch stride 276 float2 -> max 2-way bank aliasing (free, m136).
__global__ __launch_bounds__(256) void fft_filter(
    unsigned short* __restrict__ h, const float* __restrict__ fre,
    const float* __restrict__ fim) {
  __shared__ float2 S[16 * 276];
  const int tid = threadIdx.x;
  const int p = tid >> 4;
  const int q = tid & 15;
  const size_t gp = (size_t)blockIdx.x * 16 + p;
  const int sb = p * 276;

  // phase 1: row FFT (along c), row q
  {
    const unsigned short* row = h + gp * 256 + q * 16;
    ushort8 v0 = ((const ushort8*)row)[0];
    ushort8 v1 = ((const ushort8*)row)[1];
    float xr[16], xi[16], Xr[16], Xi[16];
#pragma unroll
    for (int j = 0; j < 8; ++j) {
      xr[j] = bf16_to_f32(v0[j]);
      xr[j + 8] = bf16_to_f32(v1[j]);
    }
#pragma unroll
    for (int j = 0; j < 16; ++j) xi[j] = 0.f;
    dft16(xr, xi, Xr, Xi, -1.f);
#pragma unroll
    for (int u = 0; u < 16; ++u) S[sb + q * 17 + u] = make_float2(Xr[u], Xi[u]);
  }
  __syncthreads();

  // phase 2: col FFT, filter multiply, col IFFT; column q
  {
    float xr[16], xi[16], Xr[16], Xi[16];
#pragma unroll
    for (int k = 0; k < 16; ++k) {
      float2 t = S[sb + k * 17 + q];
      xr[k] = t.x; xi[k] = t.y;
    }
    dft16(xr, xi, Xr, Xi, -1.f);
#pragma unroll
    for (int v = 0; v < 16; ++v) {
      float fr = fre[v * 16 + q], fi = fim[v * 16 + q];
      float tr = Xr[v] * fr - Xi[v] * fi;
      float ti = Xr[v] * fi + Xi[v] * fr;
      xr[v] = tr; xi[v] = ti;
    }
    dft16(xr, xi, Xr, Xi, 1.f);
#pragma unroll
    for (int r = 0; r < 16; ++r) S[sb + r * 17 + q] = make_float2(Xr[r], Xi[r]);
  }
  __syncthreads();

  // phase 3: row IFFT, scale 1/256, abs, store bf16; row q
  {
    float xr[16], xi[16], Xr[16], Xi[16];
#pragma unroll
    for (int u = 0; u < 16; ++u) {
      float2 t = S[sb + q * 17 + u];
      xr[u] = t.x; xi[u] = t.y;
    }
    dft16(xr, xi, Xr, Xi, 1.f);
    ushort8 o0, o1;
#pragma unroll
    for (int c = 0; c < 8; ++c) {
      float a0 = sqrtf(Xr[c] * Xr[c] + Xi[c] * Xi[c]) * (1.f / 256.f);
      float a1 = sqrtf(Xr[c + 8] * Xr[c + 8] + Xi[c + 8] * Xi[c + 8]) * (1.f / 256.f);
      o0[c] = f32_to_bf16(a0);
      o1[c] = f32_to_bf16(a1);
    }
    unsigned short* row = h + gp * 256 + q * 16;
    ((ushort8*)row)[0] = o0;
    ((ushort8*)row)[1] = o1;
  }
}

// ---------------- launcher ---------------------------------------------------
extern "C" void kernel_launch(void* const* d_in, const int* in_sizes, int n_in,
                              void* d_out, int out_size, void* d_ws,
                              size_t ws_size, hipStream_t stream) {
  const float* x   = (const float*)d_in[0];
  const float* We  = (const float*)d_in[1];
  const float* be  = (const float*)d_in[2];
  const float* fre = (const float*)d_in[3];
  const float* fim = (const float*)d_in[4];
  const float* Wd  = (const float*)d_in[5];
  const float* bd  = (const float*)d_in[6];

  const int E = 768, C = 768;                  // E = embed, C = ch*ps*ps
  const int nX = in_sizes[0];                  // M*E = 19,267,584
  const int M  = nX / E;                       // 25088 = 196 * 128
  const int nW = E * C;                        // 589,824

  char* w = (char*)d_ws;
  unsigned short* xb  = (unsigned short*)w;
  unsigned short* Web = (unsigned short*)(w + (size_t)nX * 2);
  unsigned short* Wdb = (unsigned short*)(w + (size_t)nX * 2 + (size_t)nW * 2);
  unsigned short* hb  = (unsigned short*)(w + (size_t)nX * 2 + (size_t)nW * 4);

  cvt_f32_bf16<<<(nX / 8 + 255) / 256, 256, 0, stream>>>(x, xb, nX / 8);
  cvt_f32_bf16<<<(nW / 8 + 255) / 256, 256, 0, stream>>>(We, Web, nW / 8);
  cvt_f32_bf16<<<(nW / 8 + 255) / 256, 256, 0, stream>>>(Wd, Wdb, nW / 8);

  // h = x @ We^T + be   (bf16 out, in ws)
  dim3 g1(C / 128, M / 128);
  gemm_bt<1><<<g1, 256, 0, stream>>>(xb, Web, be, hb, M, C, E);

  // per-patch fft2 -> filter -> ifft2 -> abs, in place on hb
  const int nPatchCh = M * 3;                  // 75,264
  fft_filter<<<nPatchCh / 16, 256, 0, stream>>>(hb, fre, fim);

  // out = a @ Wd^T + bd  (f32 out)
  dim3 g2(E / 128, M / 128);
  gemm_bt<0><<<g2, 256, 0, stream>>>(hb, Wdb, bd, (float*)d_out, M, E, C);
}

// Round 2
// 156.129 us; speedup vs baseline: 1.2794x; 1.2794x over previous
//
#include <hip/hip_runtime.h>

typedef short short8 __attribute__((ext_vector_type(8)));
typedef unsigned short ushort8 __attribute__((ext_vector_type(8)));
typedef float f32x4 __attribute__((ext_vector_type(4)));

__device__ __forceinline__ unsigned short f32_to_bf16(float f) {
  unsigned u = __float_as_uint(f);
  unsigned r = 0x7fffu + ((u >> 16) & 1u);
  return (unsigned short)((u + r) >> 16);
}
__device__ __forceinline__ float bf16_to_f32(unsigned short h) {
  return __uint_as_float(((unsigned)h) << 16);
}

// ---------------- f32 -> bf16 convert (vectorized, 8 elems/thread) ----------
__global__ void cvt_f32_bf16(const float* __restrict__ s,
                             unsigned short* __restrict__ d, int n8) {
  int i = blockIdx.x * blockDim.x + threadIdx.x;
  if (i >= n8) return;
  const float4* sp = (const float4*)s;
  float4 a = sp[2 * i], b = sp[2 * i + 1];
  ushort8 o;
  o[0] = f32_to_bf16(a.x); o[1] = f32_to_bf16(a.y);
  o[2] = f32_to_bf16(a.z); o[3] = f32_to_bf16(a.w);
  o[4] = f32_to_bf16(b.x); o[5] = f32_to_bf16(b.y);
  o[6] = f32_to_bf16(b.z); o[7] = f32_to_bf16(b.w);
  ((ushort8*)d)[i] = o;
}

// ---------------- async global->LDS (16B/lane, wave-uniform LDS base) -------
__device__ __forceinline__ void gload_lds16(const void* g, void* l) {
  auto* gp = (const __attribute__((address_space(1))) uint32_t*)((uintptr_t)g);
  auto* lp = (__attribute__((address_space(3))) uint32_t*)(uint32_t)(uintptr_t)l;
  __builtin_amdgcn_global_load_lds(gp, lp, 16, 0, 0);
}

// ---------------- bf16 MFMA GEMM, C = A * B^T + bias ------------------------
// A [M,K] bf16 row-major, B [N,K] bf16 row-major. 128x128 tile, BK=64,
// 4 waves. 2-phase prefetch (T3 minimum), double-buffered LDS.
// LDS XOR-swizzle via pre-swizzled global source (rule #21) + swizzled read.
// XCD-chunked blockIdx swizzle (grid must be %8==0).
template <int OUT_BF16>
__global__ __launch_bounds__(256) void gemm_bt(
    const unsigned short* __restrict__ A, const unsigned short* __restrict__ B,
    const float* __restrict__ bias, void* __restrict__ out,
    int M, int N, int K, int nbx) {
  __shared__ __align__(16) unsigned short As[2][128 * 64];
  __shared__ __align__(16) unsigned short Bs[2][128 * 64];

  const int tid = threadIdx.x;
  const int lane = tid & 63;
  const int wid = tid >> 6;
  const int wr = wid >> 1, wc = wid & 1;

  // XCD-chunked swizzle: consecutive logical tiles -> same XCD
  const int nwg = gridDim.x;
  const int cpx = nwg >> 3;
  const int bid = blockIdx.x;
  const int lid = (bid & 7) * cpx + (bid >> 3);
  const int m0 = (lid / nbx) * 128, n0 = (lid % nbx) * 128;

  const int lr8 = lane >> 3;                  // row within 8-row chunk
  const int swk = ((lane & 7) ^ lr8) * 8;     // pre-swizzled k-elem offset

  f32x4 acc[4][4] = {};

  // ---- staging: 8 x gload_lds (wave-uniform LDS base, linear dest) ----
  auto STAGE = [&](int buf, int k0) {
#pragma unroll
    for (int c = 0; c < 4; ++c) {
      const int rowc = wid * 32 + c * 8;
      gload_lds16(A + (size_t)(m0 + rowc + lr8) * K + (k0 + swk),
                  &As[buf][rowc * 64]);
      gload_lds16(B + (size_t)(n0 + rowc + lr8) * K + (k0 + swk),
                  &Bs[buf][rowc * 64]);
    }
  };

  // ---- compute one K-tile from LDS buf (swizzled reads) ----
  const int rsel = lane & 15;
  auto COMPUTE = [&](int buf) {
#pragma unroll
    for (int ks = 0; ks < 2; ++ks) {
      const int kbyte = ks * 64 + (lane >> 4) * 16;
      short8 af[4], bf[4];
#pragma unroll
      for (int m = 0; m < 4; ++m) {
        const int row = wr * 64 + m * 16 + rsel;
        af[m] = *(const short8*)((const char*)&As[buf][0] +
                                 row * 128 + (kbyte ^ ((row & 7) << 4)));
      }
#pragma unroll
      for (int n = 0; n < 4; ++n) {
        const int row = wc * 64 + n * 16 + rsel;
        bf[n] = *(const short8*)((const char*)&Bs[buf][0] +
                                 row * 128 + (kbyte ^ ((row & 7) << 4)));
      }
#pragma unroll
      for (int m = 0; m < 4; ++m)
#pragma unroll
        for (int n = 0; n < 4; ++n)
          acc[m][n] = __builtin_amdgcn_mfma_f32_16x16x32_bf16(
              af[m], bf[n], acc[m][n], 0, 0, 0);
    }
  };

  // ---- 2-phase pipelined K loop ----
  const int nk = K >> 6;
  STAGE(0, 0);
  __syncthreads();  // drains vmcnt(0): tile 0 resident
  int cur = 0;
  for (int t = 1; t < nk; ++t) {
    STAGE(cur ^ 1, t * 64);  // issue next tile's loads first
    COMPUTE(cur);            // MFMA hides the load latency
    __syncthreads();         // drains vmcnt: next tile resident; cur reads done
    cur ^= 1;
  }
  COMPUTE(cur);

  // C/D layout (m89-verified): col = lane&15, row = (lane>>4)*4 + j
  const int fr = lane & 15, fq = lane >> 4;
#pragma unroll
  for (int n = 0; n < 4; ++n) {
    const int gcol = n0 + wc * 64 + n * 16 + fr;
    const float bv = bias[gcol];
#pragma unroll
    for (int m = 0; m < 4; ++m) {
      const int grow = m0 + wr * 64 + m * 16 + fq * 4;
#pragma unroll
      for (int j = 0; j < 4; ++j) {
        float v = acc[m][n][j] + bv;
        if (OUT_BF16)
          ((unsigned short*)out)[(size_t)(grow + j) * N + gcol] = f32_to_bf16(v);
        else
          ((float*)out)[(size_t)(grow + j) * N + gcol] = v;
      }
    }
  }
}

// ---------------- 16-point DFT (radix 4x4, constant twiddles) ---------------
constexpr float C16T[16] = {
    1.f,  0.9238795325112867f,  0.7071067811865476f,  0.3826834323650898f,
    0.f, -0.3826834323650898f, -0.7071067811865476f, -0.9238795325112867f,
   -1.f, -0.9238795325112867f, -0.7071067811865476f, -0.3826834323650898f,
    0.f,  0.3826834323650898f,  0.7071067811865476f,  0.9238795325112867f};
constexpr float S16T[16] = {
    0.f,  0.3826834323650898f,  0.7071067811865476f,  0.9238795325112867f,
    1.f,  0.9238795325112867f,  0.7071067811865476f,  0.3826834323650898f,
    0.f, -0.3826834323650898f, -0.7071067811865476f, -0.9238795325112867f,
   -1.f, -0.9238795325112867f, -0.7071067811865476f, -0.3826834323650898f};

__device__ __forceinline__ void dft16(const float* xr, const float* xi,
                                      float* Xr, float* Xi, const float sgn) {
  float Tr[4][4], Ti[4][4];
#pragma unroll
  for (int c0 = 0; c0 < 4; ++c0) {
    float ar = xr[c0],      ai = xi[c0];
    float br = xr[c0 + 4],  bi = xi[c0 + 4];
    float cr = xr[c0 + 8],  ci = xi[c0 + 8];
    float dr = xr[c0 + 12], di = xi[c0 + 12];
    float Er = ar + cr, Ei = ai + ci, Fr = ar - cr, Fi = ai - ci;
    float Gr = br + dr, Gi = bi + di, Hr = br - dr, Hi = bi - di;
    Tr[c0][0] = Er + Gr; Ti[c0][0] = Ei + Gi;
    Tr[c0][2] = Er - Gr; Ti[c0][2] = Ei - Gi;
    float wHr = -sgn * Hi, wHi = sgn * Hr;
    Tr[c0][1] = Fr + wHr; Ti[c0][1] = Fi + wHi;
    Tr[c0][3] = Fr - wHr; Ti[c0][3] = Fi - wHi;
  }
#pragma unroll
  for (int u = 0; u < 16; ++u) {
    const int m = u & 3;
    float sr = Tr[0][m], si = Ti[0][m];
#pragma unroll
    for (int c0 = 1; c0 < 4; ++c0) {
      const int k = (u * c0) & 15;
      const float wr = C16T[k];
      const float wi = sgn * S16T[k];
      sr += wr * Tr[c0][m] - wi * Ti[c0][m];
      si += wr * Ti[c0][m] + wi * Tr[c0][m];
    }
    Xr[u] = sr; Xi[u] = si;
  }
}

// ---------------- per-patch fft2 -> filter -> ifft2 -> abs (in place) -------
__global__ __launch_bounds__(256) void fft_filter(
    unsigned short* __restrict__ h, const float* __restrict__ fre,
    const float* __restrict__ fim) {
  __shared__ float2 S[16 * 276];
  const int tid = threadIdx.x;
  const int p = tid >> 4;
  const int q = tid & 15;
  const size_t gp = (size_t)blockIdx.x * 16 + p;
  const int sb = p * 276;

  {
    const unsigned short* row = h + gp * 256 + q * 16;
    ushort8 v0 = ((const ushort8*)row)[0];
    ushort8 v1 = ((const ushort8*)row)[1];
    float xr[16], xi[16], Xr[16], Xi[16];
#pragma unroll
    for (int j = 0; j < 8; ++j) {
      xr[j] = bf16_to_f32(v0[j]);
      xr[j + 8] = bf16_to_f32(v1[j]);
    }
#pragma unroll
    for (int j = 0; j < 16; ++j) xi[j] = 0.f;
    dft16(xr, xi, Xr, Xi, -1.f);
#pragma unroll
    for (int u = 0; u < 16; ++u) S[sb + q * 17 + u] = make_float2(Xr[u], Xi[u]);
  }
  __syncthreads();

  {
    float xr[16], xi[16], Xr[16], Xi[16];
#pragma unroll
    for (int k = 0; k < 16; ++k) {
      float2 t = S[sb + k * 17 + q];
      xr[k] = t.x; xi[k] = t.y;
    }
    dft16(xr, xi, Xr, Xi, -1.f);
#pragma unroll
    for (int v = 0; v < 16; ++v) {
      float fr = fre[v * 16 + q], fi = fim[v * 16 + q];
      float tr = Xr[v] * fr - Xi[v] * fi;
      float ti = Xr[v] * fi + Xi[v] * fr;
      xr[v] = tr; xi[v] = ti;
    }
    dft16(xr, xi, Xr, Xi, 1.f);
#pragma unroll
    for (int r = 0; r < 16; ++r) S[sb + r * 17 + q] = make_float2(Xr[r], Xi[r]);
  }
  __syncthreads();

  {
    float xr[16], xi[16], Xr[16], Xi[16];
#pragma unroll
    for (int u = 0; u < 16; ++u) {
      float2 t = S[sb + q * 17 + u];
      xr[u] = t.x; xi[u] = t.y;
    }
    dft16(xr, xi, Xr, Xi, 1.f);
    ushort8 o0, o1;
#pragma unroll
    for (int c = 0; c < 8; ++c) {
      float a0 = sqrtf(Xr[c] * Xr[c] + Xi[c] * Xi[c]) * (1.f / 256.f);
      float a1 = sqrtf(Xr[c + 8] * Xr[c + 8] + Xi[c + 8] * Xi[c + 8]) * (1.f / 256.f);
      o0[c] = f32_to_bf16(a0);
      o1[c] = f32_to_bf16(a1);
    }
    unsigned short* row = h + gp * 256 + q * 16;
    ((ushort8*)row)[0] = o0;
    ((ushort8*)row)[1] = o1;
  }
}

// ---------------- launcher ---------------------------------------------------
extern "C" void kernel_launch(void* const* d_in, const int* in_sizes, int n_in,
                              void* d_out, int out_size, void* d_ws,
                              size_t ws_size, hipStream_t stream) {
  const float* x   = (const float*)d_in[0];
  const float* We  = (const float*)d_in[1];
  const float* be  = (const float*)d_in[2];
  const float* fre = (const float*)d_in[3];
  const float* fim = (const float*)d_in[4];
  const float* Wd  = (const float*)d_in[5];
  const float* bd  = (const float*)d_in[6];

  const int E = 768, C = 768;
  const int nX = in_sizes[0];                  // 19,267,584
  const int M  = nX / E;                       // 25088
  const int nW = E * C;

  char* w = (char*)d_ws;
  unsigned short* xb  = (unsigned short*)w;
  unsigned short* Web = (unsigned short*)(w + (size_t)nX * 2);
  unsigned short* Wdb = (unsigned short*)(w + (size_t)nX * 2 + (size_t)nW * 2);
  unsigned short* hb  = (unsigned short*)(w + (size_t)nX * 2 + (size_t)nW * 4);

  cvt_f32_bf16<<<(nX / 8 + 255) / 256, 256, 0, stream>>>(x, xb, nX / 8);
  cvt_f32_bf16<<<(nW / 8 + 255) / 256, 256, 0, stream>>>(We, Web, nW / 8);
  cvt_f32_bf16<<<(nW / 8 + 255) / 256, 256, 0, stream>>>(Wd, Wdb, nW / 8);

  // h = x @ We^T + be   (bf16 out, in ws); grid 1-D, %8==0 (1176 = 8*147)
  const int nbx1 = C / 128;
  gemm_bt<1><<<nbx1 * (M / 128), 256, 0, stream>>>(xb, Web, be, hb, M, C, E, nbx1);

  // per-patch fft2 -> filter -> ifft2 -> abs, in place on hb
  fft_filter<<<(M * 3) / 16, 256, 0, stream>>>(hb, fre, fim);

  // out = a @ Wd^T + bd  (f32 out)
  const int nbx2 = E / 128;
  gemm_bt<0><<<nbx2 * (M / 128), 256, 0, stream>>>(hb, Wdb, bd, (float*)d_out, M, E, C, nbx2);
}

// Round 3
// 154.100 us; speedup vs baseline: 1.2962x; 1.0132x over previous
//
#include <hip/hip_runtime.h>

typedef short short8 __attribute__((ext_vector_type(8)));
typedef unsigned short ushort8 __attribute__((ext_vector_type(8)));
typedef float f32x4 __attribute__((ext_vector_type(4)));

__device__ __forceinline__ unsigned short f32_to_bf16(float f) {
  unsigned u = __float_as_uint(f);
  unsigned r = 0x7fffu + ((u >> 16) & 1u);
  return (unsigned short)((u + r) >> 16);
}
__device__ __forceinline__ float bf16_to_f32(unsigned short h) {
  return __uint_as_float(((unsigned)h) << 16);
}

// ---------------- f32 -> bf16 convert (vectorized, 8 elems/thread) ----------
__global__ void cvt_f32_bf16(const float* __restrict__ s,
                             unsigned short* __restrict__ d, int n8) {
  int i = blockIdx.x * blockDim.x + threadIdx.x;
  if (i >= n8) return;
  const float4* sp = (const float4*)s;
  float4 a = sp[2 * i], b = sp[2 * i + 1];
  ushort8 o;
  o[0] = f32_to_bf16(a.x); o[1] = f32_to_bf16(a.y);
  o[2] = f32_to_bf16(a.z); o[3] = f32_to_bf16(a.w);
  o[4] = f32_to_bf16(b.x); o[5] = f32_to_bf16(b.y);
  o[6] = f32_to_bf16(b.z); o[7] = f32_to_bf16(b.w);
  ((ushort8*)d)[i] = o;
}

// ---------------- async global->LDS (16B/lane, wave-uniform LDS base) -------
__device__ __forceinline__ void gload_lds16(const void* g, void* l) {
  auto* gp = (const __attribute__((address_space(1))) uint32_t*)((uintptr_t)g);
  auto* lp = (__attribute__((address_space(3))) uint32_t*)(uint32_t)(uintptr_t)l;
  __builtin_amdgcn_global_load_lds(gp, lp, 16, 0, 0);
}

// ---------------- 16-point DFT (radix 4x4, constant twiddles) ---------------
constexpr float C16T[16] = {
    1.f,  0.9238795325112867f,  0.7071067811865476f,  0.3826834323650898f,
    0.f, -0.3826834323650898f, -0.7071067811865476f, -0.9238795325112867f,
   -1.f, -0.9238795325112867f, -0.7071067811865476f, -0.3826834323650898f,
    0.f,  0.3826834323650898f,  0.7071067811865476f,  0.9238795325112867f};
constexpr float S16T[16] = {
    0.f,  0.3826834323650898f,  0.7071067811865476f,  0.9238795325112867f,
    1.f,  0.9238795325112867f,  0.7071067811865476f,  0.3826834323650898f,
    0.f, -0.3826834323650898f, -0.7071067811865476f, -0.9238795325112867f,
   -1.f, -0.9238795325112867f, -0.7071067811865476f, -0.3826834323650898f};

__device__ __forceinline__ void dft16(const float* xr, const float* xi,
                                      float* Xr, float* Xi, const float sgn) {
  float Tr[4][4], Ti[4][4];
#pragma unroll
  for (int c0 = 0; c0 < 4; ++c0) {
    float ar = xr[c0],      ai = xi[c0];
    float br = xr[c0 + 4],  bi = xi[c0 + 4];
    float cr = xr[c0 + 8],  ci = xi[c0 + 8];
    float dr = xr[c0 + 12], di = xi[c0 + 12];
    float Er = ar + cr, Ei = ai + ci, Fr = ar - cr, Fi = ai - ci;
    float Gr = br + dr, Gi = bi + di, Hr = br - dr, Hi = bi - di;
    Tr[c0][0] = Er + Gr; Ti[c0][0] = Ei + Gi;
    Tr[c0][2] = Er - Gr; Ti[c0][2] = Ei - Gi;
    float wHr = -sgn * Hi, wHi = sgn * Hr;
    Tr[c0][1] = Fr + wHr; Ti[c0][1] = Fi + wHi;
    Tr[c0][3] = Fr - wHr; Ti[c0][3] = Fi - wHi;
  }
#pragma unroll
  for (int u = 0; u < 16; ++u) {
    const int m = u & 3;
    float sr = Tr[0][m], si = Ti[0][m];
#pragma unroll
    for (int c0 = 1; c0 < 4; ++c0) {
      const int k = (u * c0) & 15;
      const float wr = C16T[k];
      const float wi = sgn * S16T[k];
      sr += wr * Tr[c0][m] - wi * Ti[c0][m];
      si += wr * Ti[c0][m] + wi * Tr[c0][m];
    }
    Xr[u] = sr; Xi[u] = si;
  }
}

// ---------------- fold spectral filter into encoder weights -----------------
// For each (ch, e): take the 256-pixel column of We (or be), apply
// ifft2(fft2(.)*filt)/256, write complex result to Wre/Wim (bf16) or
// be_re/be_im (f32). 16 patches per 256-thread block; items:
//   [0, 2304)      -> We column (e = item/3, ch = item%3)
//   [2304, 2307)   -> be channel (ch = item-2304)
//   [2307, 2320)   -> dummy (compute, no store)
__global__ __launch_bounds__(256) void fold_filter(
    const float* __restrict__ We, const float* __restrict__ be,
    const float* __restrict__ fre, const float* __restrict__ fim,
    unsigned short* __restrict__ Wre, unsigned short* __restrict__ Wim,
    float* __restrict__ be_re, float* __restrict__ be_im) {
  __shared__ float2 S[16 * 276];
  const int tid = threadIdx.x;
  const int p = tid >> 4;
  const int q = tid & 15;
  const int item = blockIdx.x * 16 + p;
  const bool isW = item < 2304;
  const bool isB = (item >= 2304) && (item < 2307);
  const int e = isW ? (item / 3) : 0;
  const int ch = isW ? (item % 3) : (isB ? (item - 2304) : 0);
  const int sb = p * 276;

  // phase 1: row q forward DFT along pixels (axis -1)
  {
    float xr[16], xi[16], Xr[16], Xi[16];
#pragma unroll
    for (int c = 0; c < 16; ++c) {
      const int crow = ch * 256 + q * 16 + c;
      xr[c] = isW ? We[(size_t)crow * 768 + e] : be[crow];
      xi[c] = 0.f;
    }
    dft16(xr, xi, Xr, Xi, -1.f);
#pragma unroll
    for (int u = 0; u < 16; ++u) S[sb + q * 17 + u] = make_float2(Xr[u], Xi[u]);
  }
  __syncthreads();

  // phase 2: column q: forward DFT (axis -2), filter, inverse DFT
  {
    float xr[16], xi[16], Xr[16], Xi[16];
#pragma unroll
    for (int k = 0; k < 16; ++k) {
      float2 t = S[sb + k * 17 + q];
      xr[k] = t.x; xi[k] = t.y;
    }
    dft16(xr, xi, Xr, Xi, -1.f);
#pragma unroll
    for (int v = 0; v < 16; ++v) {
      float fr = fre[v * 16 + q], fi = fim[v * 16 + q];
      float tr = Xr[v] * fr - Xi[v] * fi;
      float ti = Xr[v] * fi + Xi[v] * fr;
      xr[v] = tr; xi[v] = ti;
    }
    dft16(xr, xi, Xr, Xi, 1.f);
#pragma unroll
    for (int r = 0; r < 16; ++r) S[sb + r * 17 + q] = make_float2(Xr[r], Xi[r]);
  }
  __syncthreads();

  // phase 3: row q inverse DFT along pixels, scale 1/256, store complex
  {
    float xr[16], xi[16], Xr[16], Xi[16];
#pragma unroll
    for (int u = 0; u < 16; ++u) {
      float2 t = S[sb + q * 17 + u];
      xr[u] = t.x; xi[u] = t.y;
    }
    dft16(xr, xi, Xr, Xi, 1.f);
#pragma unroll
    for (int c = 0; c < 16; ++c) {
      const int crow = ch * 256 + q * 16 + c;
      const float rr = Xr[c] * (1.f / 256.f);
      const float ri = Xi[c] * (1.f / 256.f);
      if (isW) {
        Wre[(size_t)crow * 768 + e] = f32_to_bf16(rr);
        Wim[(size_t)crow * 768 + e] = f32_to_bf16(ri);
      } else if (isB) {
        be_re[crow] = rr;
        be_im[crow] = ri;
      }
    }
  }
}

// ---------------- dual-B bf16 MFMA GEMM with |.| epilogue --------------------
// a[m,c] = sqrt( (x@Wre^T + be_re)^2 + (x@Wim^T + be_im)^2 ), bf16 out.
// Tile 128(M) x 64(N), BK=64, 4 waves (2x2), per-wave 64x32 per matrix,
// acc[4][2] x {re,im}. 2-phase prefetch, dbuf LDS, XOR-swizzle, XCD swizzle.
__global__ __launch_bounds__(256) void gemm_enc_dual(
    const unsigned short* __restrict__ A, const unsigned short* __restrict__ Bre,
    const unsigned short* __restrict__ Bim, const float* __restrict__ be_re,
    const float* __restrict__ be_im, unsigned short* __restrict__ out,
    int M, int K, int nbx) {
  __shared__ __align__(16) unsigned short As[2][128 * 64];
  __shared__ __align__(16) unsigned short Rs[2][64 * 64];
  __shared__ __align__(16) unsigned short Is[2][64 * 64];

  const int tid = threadIdx.x;
  const int lane = tid & 63;
  const int wid = tid >> 6;
  const int wr = wid >> 1, wc = wid & 1;

  const int nwg = gridDim.x;
  const int cpx = nwg >> 3;
  const int bid = blockIdx.x;
  const int lid = (bid & 7) * cpx + (bid >> 3);
  const int m0 = (lid / nbx) * 128, n0 = (lid % nbx) * 64;

  const int lr8 = lane >> 3;
  const int swk = ((lane & 7) ^ lr8) * 8;

  f32x4 accr[4][2] = {};
  f32x4 acci[4][2] = {};

  auto STAGE = [&](int buf, int k0) {
#pragma unroll
    for (int c = 0; c < 4; ++c) {
      const int rowc = wid * 32 + c * 8;
      gload_lds16(A + (size_t)(m0 + rowc + lr8) * K + (k0 + swk),
                  &As[buf][rowc * 64]);
    }
#pragma unroll
    for (int c = 0; c < 2; ++c) {
      const int rowc = wid * 16 + c * 8;
      gload_lds16(Bre + (size_t)(n0 + rowc + lr8) * K + (k0 + swk),
                  &Rs[buf][rowc * 64]);
      gload_lds16(Bim + (size_t)(n0 + rowc + lr8) * K + (k0 + swk),
                  &Is[buf][rowc * 64]);
    }
  };

  const int rsel = lane & 15;
  auto COMPUTE = [&](int buf) {
#pragma unroll
    for (int ks = 0; ks < 2; ++ks) {
      const int kbyte = ks * 64 + (lane >> 4) * 16;
      short8 af[4], brf[2], bif[2];
#pragma unroll
      for (int m = 0; m < 4; ++m) {
        const int row = wr * 64 + m * 16 + rsel;
        af[m] = *(const short8*)((const char*)&As[buf][0] +
                                 row * 128 + (kbyte ^ ((row & 7) << 4)));
      }
#pragma unroll
      for (int n = 0; n < 2; ++n) {
        const int row = wc * 32 + n * 16 + rsel;
        brf[n] = *(const short8*)((const char*)&Rs[buf][0] +
                                  row * 128 + (kbyte ^ ((row & 7) << 4)));
        bif[n] = *(const short8*)((const char*)&Is[buf][0] +
                                  row * 128 + (kbyte ^ ((row & 7) << 4)));
      }
#pragma unroll
      for (int m = 0; m < 4; ++m)
#pragma unroll
        for (int n = 0; n < 2; ++n) {
          accr[m][n] = __builtin_amdgcn_mfma_f32_16x16x32_bf16(
              af[m], brf[n], accr[m][n], 0, 0, 0);
          acci[m][n] = __builtin_amdgcn_mfma_f32_16x16x32_bf16(
              af[m], bif[n], acci[m][n], 0, 0, 0);
        }
    }
  };

  const int nk = K >> 6;
  STAGE(0, 0);
  __syncthreads();
  int cur = 0;
  for (int t = 1; t < nk; ++t) {
    STAGE(cur ^ 1, t * 64);
    COMPUTE(cur);
    __syncthreads();
    cur ^= 1;
  }
  COMPUTE(cur);

  const int fr = lane & 15, fq = lane >> 4;
  const int N = 768;
#pragma unroll
  for (int n = 0; n < 2; ++n) {
    const int gcol = n0 + wc * 32 + n * 16 + fr;
    const float br = be_re[gcol], bi = be_im[gcol];
#pragma unroll
    for (int m = 0; m < 4; ++m) {
      const int grow = m0 + wr * 64 + m * 16 + fq * 4;
#pragma unroll
      for (int j = 0; j < 4; ++j) {
        const float re = accr[m][n][j] + br;
        const float im = acci[m][n][j] + bi;
        out[(size_t)(grow + j) * N + gcol] = f32_to_bf16(sqrtf(re * re + im * im));
      }
    }
  }
}

// ---------------- bf16 MFMA GEMM, C = A * B^T + bias (decode) ---------------
__global__ __launch_bounds__(256) void gemm_bt(
    const unsigned short* __restrict__ A, const unsigned short* __restrict__ B,
    const float* __restrict__ bias, float* __restrict__ out,
    int M, int N, int K, int nbx) {
  __shared__ __align__(16) unsigned short As[2][128 * 64];
  __shared__ __align__(16) unsigned short Bs[2][128 * 64];

  const int tid = threadIdx.x;
  const int lane = tid & 63;
  const int wid = tid >> 6;
  const int wr = wid >> 1, wc = wid & 1;

  const int nwg = gridDim.x;
  const int cpx = nwg >> 3;
  const int bid = blockIdx.x;
  const int lid = (bid & 7) * cpx + (bid >> 3);
  const int m0 = (lid / nbx) * 128, n0 = (lid % nbx) * 128;

  const int lr8 = lane >> 3;
  const int swk = ((lane & 7) ^ lr8) * 8;

  f32x4 acc[4][4] = {};

  auto STAGE = [&](int buf, int k0) {
#pragma unroll
    for (int c = 0; c < 4; ++c) {
      const int rowc = wid * 32 + c * 8;
      gload_lds16(A + (size_t)(m0 + rowc + lr8) * K + (k0 + swk),
                  &As[buf][rowc * 64]);
      gload_lds16(B + (size_t)(n0 + rowc + lr8) * K + (k0 + swk),
                  &Bs[buf][rowc * 64]);
    }
  };

  const int rsel = lane & 15;
  auto COMPUTE = [&](int buf) {
#pragma unroll
    for (int ks = 0; ks < 2; ++ks) {
      const int kbyte = ks * 64 + (lane >> 4) * 16;
      short8 af[4], bf[4];
#pragma unroll
      for (int m = 0; m < 4; ++m) {
        const int row = wr * 64 + m * 16 + rsel;
        af[m] = *(const short8*)((const char*)&As[buf][0] +
                                 row * 128 + (kbyte ^ ((row & 7) << 4)));
      }
#pragma unroll
      for (int n = 0; n < 4; ++n) {
        const int row = wc * 64 + n * 16 + rsel;
        bf[n] = *(const short8*)((const char*)&Bs[buf][0] +
                                 row * 128 + (kbyte ^ ((row & 7) << 4)));
      }
#pragma unroll
      for (int m = 0; m < 4; ++m)
#pragma unroll
        for (int n = 0; n < 4; ++n)
          acc[m][n] = __builtin_amdgcn_mfma_f32_16x16x32_bf16(
              af[m], bf[n], acc[m][n], 0, 0, 0);
    }
  };

  const int nk = K >> 6;
  STAGE(0, 0);
  __syncthreads();
  int cur = 0;
  for (int t = 1; t < nk; ++t) {
    STAGE(cur ^ 1, t * 64);
    COMPUTE(cur);
    __syncthreads();
    cur ^= 1;
  }
  COMPUTE(cur);

  const int fr = lane & 15, fq = lane >> 4;
#pragma unroll
  for (int n = 0; n < 4; ++n) {
    const int gcol = n0 + wc * 64 + n * 16 + fr;
    const float bv = bias[gcol];
#pragma unroll
    for (int m = 0; m < 4; ++m) {
      const int grow = m0 + wr * 64 + m * 16 + fq * 4;
#pragma unroll
      for (int j = 0; j < 4; ++j)
        out[(size_t)(grow + j) * N + gcol] = acc[m][n][j] + bv;
    }
  }
}

// ---------------- launcher ---------------------------------------------------
extern "C" void kernel_launch(void* const* d_in, const int* in_sizes, int n_in,
                              void* d_out, int out_size, void* d_ws,
                              size_t ws_size, hipStream_t stream) {
  const float* x   = (const float*)d_in[0];
  const float* We  = (const float*)d_in[1];
  const float* be  = (const float*)d_in[2];
  const float* fre = (const float*)d_in[3];
  const float* fim = (const float*)d_in[4];
  const float* Wd  = (const float*)d_in[5];
  const float* bd  = (const float*)d_in[6];

  const int E = 768, C = 768;
  const int nX = in_sizes[0];                  // 19,267,584
  const int M  = nX / E;                       // 25088
  const int nW = E * C;                        // 589,824

  char* w = (char*)d_ws;
  unsigned short* xb    = (unsigned short*)w;                    // nX bf16
  unsigned short* Wdb   = (unsigned short*)(w + (size_t)nX * 2);
  unsigned short* Wre   = Wdb + nW;
  unsigned short* Wim   = Wre + nW;
  float*          be_re = (float*)(Wim + nW);
  float*          be_im = be_re + C;
  unsigned short* hb    = (unsigned short*)(be_im + C);          // nX bf16

  cvt_f32_bf16<<<(nX / 8 + 255) / 256, 256, 0, stream>>>(x, xb, nX / 8);
  cvt_f32_bf16<<<(nW / 8 + 255) / 256, 256, 0, stream>>>(Wd, Wdb, nW / 8);

  // fold ifft2(fft2(.)*filt)/256 into encoder weights: 2307 items -> 145 blocks
  fold_filter<<<145, 256, 0, stream>>>(We, be, fre, fim, Wre, Wim, be_re, be_im);

  // a = |x @ We'^T + be'|   (bf16, in ws); grid 2352 = 196*12, %8==0
  const int nbx1 = C / 64;
  gemm_enc_dual<<<nbx1 * (M / 128), 256, 0, stream>>>(xb, Wre, Wim, be_re,
                                                      be_im, hb, M, E, nbx1);

  // out = a @ Wd^T + bd  (f32)
  const int nbx2 = E / 128;
  gemm_bt<<<nbx2 * (M / 128), 256, 0, stream>>>(hb, Wdb, bd, (float*)d_out, M,
                                                E, C, nbx2);
}

// Round 4
// 152.342 us; speedup vs baseline: 1.3112x; 1.0115x over previous
//
#include <hip/hip_runtime.h>

typedef short short8 __attribute__((ext_vector_type(8)));
typedef unsigned short ushort8 __attribute__((ext_vector_type(8)));
typedef float f32x4 __attribute__((ext_vector_type(4)));

__device__ __forceinline__ unsigned short f32_to_bf16(float f) {
  unsigned u = __float_as_uint(f);
  unsigned r = 0x7fffu + ((u >> 16) & 1u);
  return (unsigned short)((u + r) >> 16);
}
__device__ __forceinline__ float bf16_to_f32(unsigned short h) {
  return __uint_as_float(((unsigned)h) << 16);
}

// ---------------- f32 -> bf16 convert (vectorized, 8 elems/thread) ----------
__global__ void cvt_f32_bf16(const float* __restrict__ s,
                             unsigned short* __restrict__ d, int n8) {
  int i = blockIdx.x * blockDim.x + threadIdx.x;
  if (i >= n8) return;
  const float4* sp = (const float4*)s;
  float4 a = sp[2 * i], b = sp[2 * i + 1];
  ushort8 o;
  o[0] = f32_to_bf16(a.x); o[1] = f32_to_bf16(a.y);
  o[2] = f32_to_bf16(a.z); o[3] = f32_to_bf16(a.w);
  o[4] = f32_to_bf16(b.x); o[5] = f32_to_bf16(b.y);
  o[6] = f32_to_bf16(b.z); o[7] = f32_to_bf16(b.w);
  ((ushort8*)d)[i] = o;
}

// ---------------- async global->LDS (16B/lane, wave-uniform LDS base) -------
__device__ __forceinline__ void gload_lds16(const void* g, void* l) {
  auto* gp = (const __attribute__((address_space(1))) uint32_t*)((uintptr_t)g);
  auto* lp = (__attribute__((address_space(3))) uint32_t*)(uint32_t)(uintptr_t)l;
  __builtin_amdgcn_global_load_lds(gp, lp, 16, 0, 0);
}

// ---------------- 16-point DFT (radix 4x4, constant twiddles) ---------------
constexpr float C16T[16] = {
    1.f,  0.9238795325112867f,  0.7071067811865476f,  0.3826834323650898f,
    0.f, -0.3826834323650898f, -0.7071067811865476f, -0.9238795325112867f,
   -1.f, -0.9238795325112867f, -0.7071067811865476f, -0.3826834323650898f,
    0.f,  0.3826834323650898f,  0.7071067811865476f,  0.9238795325112867f};
constexpr float S16T[16] = {
    0.f,  0.3826834323650898f,  0.7071067811865476f,  0.9238795325112867f,
    1.f,  0.9238795325112867f,  0.7071067811865476f,  0.3826834323650898f,
    0.f, -0.3826834323650898f, -0.7071067811865476f, -0.9238795325112867f,
   -1.f, -0.9238795325112867f, -0.7071067811865476f, -0.3826834323650898f};

__device__ __forceinline__ void dft16(const float* xr, const float* xi,
                                      float* Xr, float* Xi, const float sgn) {
  float Tr[4][4], Ti[4][4];
#pragma unroll
  for (int c0 = 0; c0 < 4; ++c0) {
    float ar = xr[c0],      ai = xi[c0];
    float br = xr[c0 + 4],  bi = xi[c0 + 4];
    float cr = xr[c0 + 8],  ci = xi[c0 + 8];
    float dr = xr[c0 + 12], di = xi[c0 + 12];
    float Er = ar + cr, Ei = ai + ci, Fr = ar - cr, Fi = ai - ci;
    float Gr = br + dr, Gi = bi + di, Hr = br - dr, Hi = bi - di;
    Tr[c0][0] = Er + Gr; Ti[c0][0] = Ei + Gi;
    Tr[c0][2] = Er - Gr; Ti[c0][2] = Ei - Gi;
    float wHr = -sgn * Hi, wHi = sgn * Hr;
    Tr[c0][1] = Fr + wHr; Ti[c0][1] = Fi + wHi;
    Tr[c0][3] = Fr - wHr; Ti[c0][3] = Fi - wHi;
  }
#pragma unroll
  for (int u = 0; u < 16; ++u) {
    const int m = u & 3;
    float sr = Tr[0][m], si = Ti[0][m];
#pragma unroll
    for (int c0 = 1; c0 < 4; ++c0) {
      const int k = (u * c0) & 15;
      const float wr = C16T[k];
      const float wi = sgn * S16T[k];
      sr += wr * Tr[c0][m] - wi * Ti[c0][m];
      si += wr * Ti[c0][m] + wi * Tr[c0][m];
    }
    Xr[u] = sr; Xi[u] = si;
  }
}

// ---------------- fold spectral filter into encoder weights -----------------
// Writes interleaved B'' [1536][768] bf16: for output-channel c (0..767),
//   re -> row (c>>5)*64 + (c&31),  im -> row (c>>5)*64 + 32 + (c&31).
// So any 64-row group g covers {re,im} of cols [g*32, g*32+32).
__global__ __launch_bounds__(256) void fold_filter(
    const float* __restrict__ We, const float* __restrict__ be,
    const float* __restrict__ fre, const float* __restrict__ fim,
    unsigned short* __restrict__ Bpp, float* __restrict__ be_re,
    float* __restrict__ be_im) {
  __shared__ float2 S[16 * 276];
  const int tid = threadIdx.x;
  const int p = tid >> 4;
  const int q = tid & 15;
  const int item = blockIdx.x * 16 + p;
  const bool isW = item < 2304;
  const bool isB = (item >= 2304) && (item < 2307);
  const int e = isW ? (item / 3) : 0;
  const int ch = isW ? (item % 3) : (isB ? (item - 2304) : 0);
  const int sb = p * 276;

  // phase 1: row q forward DFT along pixels (axis -1)
  {
    float xr[16], xi[16], Xr[16], Xi[16];
#pragma unroll
    for (int c = 0; c < 16; ++c) {
      const int crow = ch * 256 + q * 16 + c;
      xr[c] = isW ? We[(size_t)crow * 768 + e] : be[crow];
      xi[c] = 0.f;
    }
    dft16(xr, xi, Xr, Xi, -1.f);
#pragma unroll
    for (int u = 0; u < 16; ++u) S[sb + q * 17 + u] = make_float2(Xr[u], Xi[u]);
  }
  __syncthreads();

  // phase 2: column q: forward DFT (axis -2), filter, inverse DFT
  {
    float xr[16], xi[16], Xr[16], Xi[16];
#pragma unroll
    for (int k = 0; k < 16; ++k) {
      float2 t = S[sb + k * 17 + q];
      xr[k] = t.x; xi[k] = t.y;
    }
    dft16(xr, xi, Xr, Xi, -1.f);
#pragma unroll
    for (int v = 0; v < 16; ++v) {
      float fr = fre[v * 16 + q], fi = fim[v * 16 + q];
      float tr = Xr[v] * fr - Xi[v] * fi;
      float ti = Xr[v] * fi + Xi[v] * fr;
      xr[v] = tr; xi[v] = ti;
    }
    dft16(xr, xi, Xr, Xi, 1.f);
#pragma unroll
    for (int r = 0; r < 16; ++r) S[sb + r * 17 + q] = make_float2(Xr[r], Xi[r]);
  }
  __syncthreads();

  // phase 3: row q inverse DFT, scale 1/256, store interleaved complex
  {
    float xr[16], xi[16], Xr[16], Xi[16];
#pragma unroll
    for (int u = 0; u < 16; ++u) {
      float2 t = S[sb + q * 17 + u];
      xr[u] = t.x; xi[u] = t.y;
    }
    dft16(xr, xi, Xr, Xi, 1.f);
#pragma unroll
    for (int c = 0; c < 16; ++c) {
      const int crow = ch * 256 + q * 16 + c;
      const float rr = Xr[c] * (1.f / 256.f);
      const float ri = Xi[c] * (1.f / 256.f);
      if (isW) {
        const size_t rre = (size_t)(crow >> 5) * 64 + (crow & 31);
        Bpp[(rre)*768 + e]      = f32_to_bf16(rr);
        Bpp[(rre + 32)*768 + e] = f32_to_bf16(ri);
      } else if (isB) {
        be_re[crow] = rr;
        be_im[crow] = ri;
      }
    }
  }
}

// ---------------- encode GEMM: exact gemm_bt structure, magnitude epilogue --
// A [M,768] bf16, B'' [1536,768] bf16 (interleaved re/im). 128x128 tile,
// BK=64, 4 waves, 2-phase prefetch, dbuf LDS, XOR-swizzle, XCD swizzle.
// Epilogue: out[row, col] = sqrt((re+br)^2 + (im+bi)^2) bf16, N=768.
__global__ __launch_bounds__(256) void gemm_enc(
    const unsigned short* __restrict__ A, const unsigned short* __restrict__ B,
    const float* __restrict__ be_re, const float* __restrict__ be_im,
    unsigned short* __restrict__ out, int M, int K, int nbx) {
  __shared__ __align__(16) unsigned short As[2][128 * 64];
  __shared__ __align__(16) unsigned short Bs[2][128 * 64];

  const int tid = threadIdx.x;
  const int lane = tid & 63;
  const int wid = tid >> 6;
  const int wr = wid >> 1, wc = wid & 1;

  const int nwg = gridDim.x;
  const int cpx = nwg >> 3;
  const int bid = blockIdx.x;
  const int lid = (bid & 7) * cpx + (bid >> 3);
  const int m0 = (lid / nbx) * 128, n0 = (lid % nbx) * 128;

  const int lr8 = lane >> 3;
  const int swk = ((lane & 7) ^ lr8) * 8;

  f32x4 acc[4][4] = {};

  auto STAGE = [&](int buf, int k0) {
#pragma unroll
    for (int c = 0; c < 4; ++c) {
      const int rowc = wid * 32 + c * 8;
      gload_lds16(A + (size_t)(m0 + rowc + lr8) * K + (k0 + swk),
                  &As[buf][rowc * 64]);
      gload_lds16(B + (size_t)(n0 + rowc + lr8) * K + (k0 + swk),
                  &Bs[buf][rowc * 64]);
    }
  };

  const int rsel = lane & 15;
  auto COMPUTE = [&](int buf) {
#pragma unroll
    for (int ks = 0; ks < 2; ++ks) {
      const int kbyte = ks * 64 + (lane >> 4) * 16;
      short8 af[4], bf[4];
#pragma unroll
      for (int m = 0; m < 4; ++m) {
        const int row = wr * 64 + m * 16 + rsel;
        af[m] = *(const short8*)((const char*)&As[buf][0] +
                                 row * 128 + (kbyte ^ ((row & 7) << 4)));
      }
#pragma unroll
      for (int n = 0; n < 4; ++n) {
        const int row = wc * 64 + n * 16 + rsel;
        bf[n] = *(const short8*)((const char*)&Bs[buf][0] +
                                 row * 128 + (kbyte ^ ((row & 7) << 4)));
      }
#pragma unroll
      for (int m = 0; m < 4; ++m)
#pragma unroll
        for (int n = 0; n < 4; ++n)
          acc[m][n] = __builtin_amdgcn_mfma_f32_16x16x32_bf16(
              af[m], bf[n], acc[m][n], 0, 0, 0);
    }
  };

  const int nk = K >> 6;
  STAGE(0, 0);
  __syncthreads();
  int cur = 0;
  for (int t = 1; t < nk; ++t) {
    STAGE(cur ^ 1, t * 64);
    COMPUTE(cur);
    __syncthreads();
    cur ^= 1;
  }
  COMPUTE(cur);

  // acc[m][n] (n=0,1) = re, acc[m][n+2] = im of the same output column.
  const int fr = lane & 15, fq = lane >> 4;
  const int cbase = (n0 + wc * 64) >> 1;  // 64 B''-rows -> 32 output cols
#pragma unroll
  for (int n = 0; n < 2; ++n) {
    const int gcol = cbase + n * 16 + fr;
    const float br = be_re[gcol], bi = be_im[gcol];
#pragma unroll
    for (int m = 0; m < 4; ++m) {
      const int grow = m0 + wr * 64 + m * 16 + fq * 4;
#pragma unroll
      for (int j = 0; j < 4; ++j) {
        const float re = acc[m][n][j] + br;
        const float im = acc[m][n + 2][j] + bi;
        out[(size_t)(grow + j) * 768 + gcol] =
            f32_to_bf16(sqrtf(re * re + im * im));
      }
    }
  }
}

// ---------------- decode GEMM: C = A * B^T + bias, f32 out ------------------
__global__ __launch_bounds__(256) void gemm_bt(
    const unsigned short* __restrict__ A, const unsigned short* __restrict__ B,
    const float* __restrict__ bias, float* __restrict__ out,
    int M, int N, int K, int nbx) {
  __shared__ __align__(16) unsigned short As[2][128 * 64];
  __shared__ __align__(16) unsigned short Bs[2][128 * 64];

  const int tid = threadIdx.x;
  const int lane = tid & 63;
  const int wid = tid >> 6;
  const int wr = wid >> 1, wc = wid & 1;

  const int nwg = gridDim.x;
  const int cpx = nwg >> 3;
  const int bid = blockIdx.x;
  const int lid = (bid & 7) * cpx + (bid >> 3);
  const int m0 = (lid / nbx) * 128, n0 = (lid % nbx) * 128;

  const int lr8 = lane >> 3;
  const int swk = ((lane & 7) ^ lr8) * 8;

  f32x4 acc[4][4] = {};

  auto STAGE = [&](int buf, int k0) {
#pragma unroll
    for (int c = 0; c < 4; ++c) {
      const int rowc = wid * 32 + c * 8;
      gload_lds16(A + (size_t)(m0 + rowc + lr8) * K + (k0 + swk),
                  &As[buf][rowc * 64]);
      gload_lds16(B + (size_t)(n0 + rowc + lr8) * K + (k0 + swk),
                  &Bs[buf][rowc * 64]);
    }
  };

  const int rsel = lane & 15;
  auto COMPUTE = [&](int buf) {
#pragma unroll
    for (int ks = 0; ks < 2; ++ks) {
      const int kbyte = ks * 64 + (lane >> 4) * 16;
      short8 af[4], bf[4];
#pragma unroll
      for (int m = 0; m < 4; ++m) {
        const int row = wr * 64 + m * 16 + rsel;
        af[m] = *(const short8*)((const char*)&As[buf][0] +
                                 row * 128 + (kbyte ^ ((row & 7) << 4)));
      }
#pragma unroll
      for (int n = 0; n < 4; ++n) {
        const int row = wc * 64 + n * 16 + rsel;
        bf[n] = *(const short8*)((const char*)&Bs[buf][0] +
                                 row * 128 + (kbyte ^ ((row & 7) << 4)));
      }
#pragma unroll
      for (int m = 0; m < 4; ++m)
#pragma unroll
        for (int n = 0; n < 4; ++n)
          acc[m][n] = __builtin_amdgcn_mfma_f32_16x16x32_bf16(
              af[m], bf[n], acc[m][n], 0, 0, 0);
    }
  };

  const int nk = K >> 6;
  STAGE(0, 0);
  __syncthreads();
  int cur = 0;
  for (int t = 1; t < nk; ++t) {
    STAGE(cur ^ 1, t * 64);
    COMPUTE(cur);
    __syncthreads();
    cur ^= 1;
  }
  COMPUTE(cur);

  const int fr = lane & 15, fq = lane >> 4;
#pragma unroll
  for (int n = 0; n < 4; ++n) {
    const int gcol = n0 + wc * 64 + n * 16 + fr;
    const float bv = bias[gcol];
#pragma unroll
    for (int m = 0; m < 4; ++m) {
      const int grow = m0 + wr * 64 + m * 16 + fq * 4;
#pragma unroll
      for (int j = 0; j < 4; ++j)
        out[(size_t)(grow + j) * N + gcol] = acc[m][n][j] + bv;
    }
  }
}

// ---------------- launcher ---------------------------------------------------
extern "C" void kernel_launch(void* const* d_in, const int* in_sizes, int n_in,
                              void* d_out, int out_size, void* d_ws,
                              size_t ws_size, hipStream_t stream) {
  const float* x   = (const float*)d_in[0];
  const float* We  = (const float*)d_in[1];
  const float* be  = (const float*)d_in[2];
  const float* fre = (const float*)d_in[3];
  const float* fim = (const float*)d_in[4];
  const float* Wd  = (const float*)d_in[5];
  const float* bd  = (const float*)d_in[6];

  const int E = 768, C = 768;
  const int nX = in_sizes[0];                  // 19,267,584
  const int M  = nX / E;                       // 25088
  const int nW = E * C;                        // 589,824

  char* w = (char*)d_ws;
  unsigned short* xb    = (unsigned short*)w;                    // nX bf16
  unsigned short* Wdb   = (unsigned short*)(w + (size_t)nX * 2); // nW bf16
  unsigned short* Bpp   = Wdb + nW;                              // 2*nW bf16
  float*          be_re = (float*)(Bpp + 2 * (size_t)nW);
  float*          be_im = be_re + C;
  unsigned short* hb    = (unsigned short*)(be_im + C);          // nX bf16

  cvt_f32_bf16<<<(nX / 8 + 255) / 256, 256, 0, stream>>>(x, xb, nX / 8);
  cvt_f32_bf16<<<(nW / 8 + 255) / 256, 256, 0, stream>>>(Wd, Wdb, nW / 8);

  // fold ifft2(fft2(.)*filt)/256 into interleaved complex encoder weights
  fold_filter<<<145, 256, 0, stream>>>(We, be, fre, fim, Bpp, be_re, be_im);

  // a = |x @ We'^T + be'|  (bf16, in ws); grid 2352 = 196*12, %8==0
  const int nbx1 = (2 * C) / 128;              // 12
  gemm_enc<<<nbx1 * (M / 128), 256, 0, stream>>>(xb, Bpp, be_re, be_im, hb, M,
                                                 E, nbx1);

  // out = a @ Wd^T + bd  (f32); grid 1176 = 196*6, %8==0
  const int nbx2 = E / 128;
  gemm_bt<<<nbx2 * (M / 128), 256, 0, stream>>>(hb, Wdb, bd, (float*)d_out, M,
                                                E, C, nbx2);
}